// Round 12
// baseline (69.691 us; speedup 1.0000x reference)
//
#include <hip/hip_runtime.h>
#include <hip/hip_fp16.h>

#define BATCH 8192
#define IN_F 128
#define OUT_F 256
#define LC 23        // grid_size + order
#define BROW 768     // bytes per (j,g) cp2 row: 16 cols x 24 slots x 2B
#define JPW 16       // j's per wave (8-way in-block K-split)

typedef _Float16 f16x8 __attribute__((ext_vector_type(8)));
typedef float f32x4 __attribute__((ext_vector_type(4)));
typedef _Float16 half2v __attribute__((ext_vector_type(2)));

// ===========================================================================
// prep_kernel: repack coeffs -> cp2 (f16 B-fragments, 24-slot rows, 1.5 MiB).
//   cp2 row (j,g): [q 3][col 16][16B]; (q,col) holds slots 8q..8q+7 of
//   output col i=g*16+col (slot >= 20 -> 0).  16x16x32 B-frag register
//   layout for lane quadrants q<3; q=3 frag unused (A there is zero).
//   (R5..R10-verified)
// ===========================================================================
__global__ __launch_bounds__(256) void prep_kernel(
    const float* __restrict__ coeffs, _Float16* __restrict__ cp2) {
    int t = blockIdx.x * 256 + threadIdx.x;   // [0, 98304)
    int col = t & 15;
    int u = t >> 4;          // [0, 6144)
    int q = u % 3;
    int v = u / 3;           // [0, 2048)
    int g = v & 15;
    int j = v >> 4;          // [0, 128)
    int i = g * 16 + col;
    int s0 = q * 8;
    const float* src = coeffs + ((size_t)i * IN_F + j) * LC;
    f16x8 w;
#pragma unroll
    for (int e = 0; e < 8; ++e) {
        int s = s0 + e;
        float f = (s < 20) ? src[s] : 0.0f;
        w[e] = (_Float16)f;
    }
    char* dst = reinterpret_cast<char*>(cp2) +
                (size_t)(j * 16 + g) * BROW + q * 256 + col * 16;
    *reinterpret_cast<f16x8*>(dst) = w;
}

// ===========================================================================
// kan_mfma8 (R8-verified, passing at 30.2 us total): out = W * C via
// mfma_f32_16x16x32_f16.
//   Block: 512 thr = 8 INDEPENDENT waves; wave ks owns j in [ks*16,ks*16+16).
//   Block tile 64 x 64 (bn in [0,4)); wave computes the full 64x64 partial
//   (mf=4 x nf=4).  Grid = 128 mb x 4 bn = 512 -> 2 blocks/CU, 16 waves/CU.
// Phase 0: meta (sigmoid/bin/weights) -> 64 KiB LDS.
// K-loop: ping-pong B-frag prefetch (2x unrolled); au rebuilt per mf.
//   q=3 lanes re-read q=2 bytes (A-frag there is structurally zero).
// Epilogue: 8-partial reduce in 2 half-passes, XOR-16 swizzle.
// ===========================================================================
__global__ __launch_bounds__(512, 4) void kan_mfma8(
    const float* __restrict__ x, const char* __restrict__ cp2,
    float* __restrict__ out) {
    __shared__ uint2 mlds[IN_F][64];   // 64 KiB: [j][row] meta

    const int tid = threadIdx.x;
    const int lane = tid & 63;
    const int ks = tid >> 6;           // wave id = K-split id [0,8)
    const int l15 = lane & 15;
    const int q = lane >> 4;
    const int q4 = q * 4;
    const int qc = (q < 3) ? q : 2;    // q=3 reads q=2's bytes (A=0 there)

    // bijective XCD swizzle (512 = 8 * 64)
    int wg = (blockIdx.x & 7) * 64 + (blockIdx.x >> 3);
    const int mb = wg >> 2;   // [0,128)
    const int bn = wg & 3;    // [0,4)
    const int b0 = mb * 64;

    // ---- Phase 0: meta for 64 rows x 128 j into LDS ----
    {
        const int row = lane;              // rows 0..63
        const int jb = ks * 16;            // 8 waves x 16 j
        const float4* xr = reinterpret_cast<const float4*>(
            x + (size_t)(b0 + row) * IN_F + jb);
#pragma unroll
        for (int u = 0; u < 4; ++u) {
            float4 xv = xr[u];
#pragma unroll
            for (int e = 0; e < 4; ++e) {
                float xvv = (e == 0) ? xv.x : (e == 1) ? xv.y
                           : (e == 2) ? xv.z : xv.w;
                float s = 1.0f / (1.0f + __expf(-xvv));
                float idxf = s * 19.0f;
                int k = (int)idxf;            // floor (idxf >= 0)
                k = (k > 18) ? 18 : k;
                float w1 = idxf - (float)k;
                float w0 = 1.0f - w1;
                unsigned u0 = __half_as_ushort(__float2half(w0));
                unsigned u1 = __half_as_ushort(__float2half(w1));
                unsigned lo, hi;
                if (k & 1) { lo = u0 << 16; hi = u1; }
                else       { lo = u0 | (u1 << 16); hi = 0u; }
                unsigned P = (unsigned)(k >> 1);
                mlds[jb + u * 4 + e][row] = uint2{lo, hi | (P << 16)};
            }
        }
    }
    __syncthreads();

    // ---- K-loop ----
    const int j0 = ks * JPW;
    const char* bbase = cp2 + (size_t)(bn * 4) * BROW + qc * 256 + l15 * 16;
    auto bld = [&](int j, int nf) {
        return *reinterpret_cast<const f16x8*>(
            bbase + (size_t)(j * 16 + nf) * BROW);
    };

    f32x4 acc[4][4];
#pragma unroll
    for (int mf = 0; mf < 4; ++mf)
#pragma unroll
        for (int nf = 0; nf < 4; ++nf) acc[mf][nf] = f32x4{0.f, 0.f, 0.f, 0.f};

    f16x8 rc[4], rn[4];
#pragma unroll
    for (int h = 0; h < 4; ++h) rc[h] = bld(j0, h);

    auto step = [&](f16x8 (&cur)[4], f16x8 (&nxt)[4], int j, int jn) {
        // prefetch next j's B-frags (land under A-build + MFMA)
#pragma unroll
        for (int h = 0; h < 4; ++h) nxt[h] = bld(jn, h);
#pragma unroll
        for (int mf = 0; mf < 4; ++mf) {
            uint2 m = mlds[j][mf * 16 + l15];
            unsigned lo = m.x;
            unsigned hi = m.y & 0xFFFFu;
            int d = (int)(m.y >> 16) - q4;
            union { uint32_t u[4]; f16x8 h; } au;
#pragma unroll
            for (int r = 0; r < 4; ++r) {
                uint32_t v = (d == r) ? lo : 0u;
                v = (d == r - 1) ? hi : v;
                au.u[r] = v;
            }
#pragma unroll
            for (int nf = 0; nf < 4; ++nf)
                acc[mf][nf] = __builtin_amdgcn_mfma_f32_16x16x32_f16(
                    au.h, cur[nf], acc[mf][nf], 0, 0, 0);
        }
    };

    for (int jj = 0; jj < JPW; jj += 2) {
        step(rc, rn, j0 + jj, j0 + jj + 1);
        step(rn, rc, j0 + jj + 1, j0 + ((jj + 2) & (JPW - 1)));  // wrap
    }

    // ---- Epilogue: reduce 8 wave-partials in 2 column-half passes ----
    __syncthreads();   // all waves done reading mlds
    float* red = reinterpret_cast<float*>(&mlds[0][0]);   // 16384 f32
#pragma unroll
    for (int p = 0; p < 2; ++p) {
        if (p) __syncthreads();   // previous pass's reads complete
        // wave ks writes its 64x32 half: C/D layout col=l15, row=q4+r
        // XOR-16 swizzle on col by (q&1): write banks 2-way (free)
#pragma unroll
        for (int mf = 0; mf < 4; ++mf)
#pragma unroll
            for (int t = 0; t < 2; ++t)
#pragma unroll
                for (int r = 0; r < 4; ++r) {
                    int colsw = (t * 16 + l15 + (q & 1) * 16) & 31;
                    red[ks * 2048 + (mf * 16 + q4 + r) * 32 + colsw] =
                        acc[mf][p * 2 + t][r];
                }
        __syncthreads();
#pragma unroll
        for (int it = 0; it < 4; ++it) {
            int idx = it * 512 + tid;   // [0,2048) = [64 rows][32 cols]
            int row = idx >> 5;
            int col = idx & 31;
            int colsw = (col + ((row >> 2) & 1) * 16) & 31;
            float s = 0.f;
#pragma unroll
            for (int w = 0; w < 8; ++w) s += red[w * 2048 + row * 32 + colsw];
            out[(size_t)(b0 + row) * OUT_F + bn * 64 + p * 32 + col] = s;
        }
    }
}

// ===========================================================================
// Fallback paths (R2-validated) — used only if d_ws is too small.
// ===========================================================================
__device__ __forceinline__ float dot2_acc(unsigned cbits, unsigned wbits,
                                          float acc) {
#if __has_builtin(__builtin_amdgcn_fdot2)
    union { unsigned u; half2v h; } c, w;
    c.u = cbits; w.u = wbits;
    return __builtin_amdgcn_fdot2(c.h, w.h, acc, false);
#else
    __half2 hc = *reinterpret_cast<const __half2*>(&cbits);
    __half2 hw = *reinterpret_cast<const __half2*>(&wbits);
    float2 fc = __half22float2(hc);
    float2 fw = __half22float2(hw);
    return acc + fc.x * fw.x + fc.y * fw.y;
#endif
}

__global__ __launch_bounds__(256) void build_ctg_kernel(
    const float* __restrict__ coeffs, unsigned short* __restrict__ ctg) {
    int tid = blockIdx.x * 256 + threadIdx.x;
    int qq = tid & 63;
    int k = (tid >> 6) % LC;
    int j = tid / (64 * LC);
    if (j >= IN_F) return;
    int k1 = (k + 1 < LC) ? (k + 1) : (LC - 1);
    union { unsigned short h[8]; uint4 v; } u;
#pragma unroll
    for (int c = 0; c < 4; ++c) {
        int i = qq * 4 + c;
        const float* base = coeffs + ((size_t)i * IN_F + j) * LC;
        u.h[2 * c]     = __half_as_ushort(__float2half(base[k]));
        u.h[2 * c + 1] = __half_as_ushort(__float2half(base[k1]));
    }
    reinterpret_cast<uint4*>(ctg)[tid] = u.v;
}

__global__ __launch_bounds__(256) void kan_main_kernel(
    const float* __restrict__ x, const char* __restrict__ ctg,
    float* __restrict__ out) {
    __shared__ unsigned metas[4][2 * IN_F];
    const int wave = threadIdx.x >> 6;
    const int lane = threadIdx.x & 63;
    const int b = blockIdx.x * 4 + wave;
    float2 xv = reinterpret_cast<const float2*>(x + (size_t)b * IN_F)[lane];
    uint4 m;
#pragma unroll
    for (int t = 0; t < 2; ++t) {
        float xs = t ? xv.y : xv.x;
        float s = 1.0f / (1.0f + __expf(-xs));
        float idxf = s * 19.0f;
        int k = (int)idxf;
        k = (k > 18) ? 18 : k;
        float w1 = idxf - (float)k;
        float w0 = 1.0f - w1;
        int j = 2 * lane + t;
        unsigned off = (unsigned)((j * LC + k) << 10);
        half2v w; w[0] = (_Float16)w0; w[1] = (_Float16)w1;
        unsigned wbits = *reinterpret_cast<unsigned*>(&w);
        if (t == 0) { m.x = off; m.y = wbits; }
        else        { m.z = off; m.w = wbits; }
    }
    reinterpret_cast<uint4*>(&metas[wave][0])[lane] = m;
    __syncthreads();
    const unsigned lanebase = lane * 16;
    const uint4* mrow = reinterpret_cast<const uint4*>(&metas[wave][0]);
    float acc0 = 0.f, acc1 = 0.f, acc2 = 0.f, acc3 = 0.f;
#pragma unroll 8
    for (int j2 = 0; j2 < IN_F / 2; ++j2) {
        uint4 mm = mrow[j2];
        {
            const uint4 e = *reinterpret_cast<const uint4*>(
                ctg + (size_t)(lanebase + mm.x));
            acc0 = dot2_acc(e.x, mm.y, acc0);
            acc1 = dot2_acc(e.y, mm.y, acc1);
            acc2 = dot2_acc(e.z, mm.y, acc2);
            acc3 = dot2_acc(e.w, mm.y, acc3);
        }
        {
            const uint4 e = *reinterpret_cast<const uint4*>(
                ctg + (size_t)(lanebase + mm.z));
            acc0 = dot2_acc(e.x, mm.w, acc0);
            acc1 = dot2_acc(e.y, mm.w, acc1);
            acc2 = dot2_acc(e.z, mm.w, acc2);
            acc3 = dot2_acc(e.w, mm.w, acc3);
        }
    }
    float4 r = make_float4(acc0, acc1, acc2, acc3);
    reinterpret_cast<float4*>(out + (size_t)b * OUT_F)[lane] = r;
}

// ===========================================================================
extern "C" void kernel_launch(void* const* d_in, const int* in_sizes, int n_in,
                              void* d_out, int out_size, void* d_ws,
                              size_t ws_size, hipStream_t stream) {
    const float* x = (const float*)d_in[0];       // [8192, 128] f32
    const float* coeffs = (const float*)d_in[1];  // [256, 128, 23] f32
    float* out = (float*)d_out;                   // [8192, 256] f32

    const size_t cp2_bytes = (size_t)IN_F * 16 * BROW;           // 1.5 MiB
    const size_t ctg_bytes = (size_t)IN_F * LC * 64 * 16;        // ~2.9 MiB

    if (d_ws != nullptr && ws_size >= cp2_bytes) {
        _Float16* cp2 = (_Float16*)d_ws;
        prep_kernel<<<384, 256, 0, stream>>>(coeffs, cp2);
        // PROBE (clean this time): triple-launch the R8-verified main kernel.
        // Idempotent (reads x/cp2, plain stores of identical values).
        // dur = p + 3m + o; R8's single-launch was p + m + o = 30.2 us
        //   =>  m = (dur - 30.2) / 2.
        kan_mfma8<<<512, 512, 0, stream>>>(x, (const char*)cp2, out);
        kan_mfma8<<<512, 512, 0, stream>>>(x, (const char*)cp2, out);
        kan_mfma8<<<512, 512, 0, stream>>>(x, (const char*)cp2, out);
    } else if (d_ws != nullptr && ws_size >= ctg_bytes) {
        char* ctg = (char*)d_ws;
        const int totalA = IN_F * LC * 64;
        build_ctg_kernel<<<(totalA + 255) / 256, 256, 0, stream>>>(
            coeffs, (unsigned short*)ctg);
        kan_main_kernel<<<BATCH / 4, 256, 0, stream>>>(x, ctg, out);
    } else {
        kan_main_kernel<<<BATCH / 4, 256, 0, stream>>>(x, (const char*)d_ws,
                                                       out);
    }
}

// Round 13
// 30.100 us; speedup vs baseline: 2.3153x; 2.3153x over previous
//
#include <hip/hip_runtime.h>
#include <hip/hip_fp16.h>

#define BATCH 8192
#define IN_F 128
#define OUT_F 256
#define LC 23        // grid_size + order
#define BROW 768     // bytes per (j,g) cp2 row: 16 cols x 24 slots x 2B
#define JPW 16       // j's per wave (8-way in-block K-split)

typedef _Float16 f16x8 __attribute__((ext_vector_type(8)));
typedef float f32x4 __attribute__((ext_vector_type(4)));
typedef _Float16 half2v __attribute__((ext_vector_type(2)));

// ===========================================================================
// prep_fast: coalesced repack coeffs -> cp2 (identical output layout to the
// R5..R12-verified prep_kernel: row (j,g) = [q 3][col 16][16B], slot>=20 -> 0).
// Each block float4-streams a contiguous 23552-B slab (256 (i,j) pairs x 23
// f32) into LDS, then each thread repacks its (i,j) into three 16-B chunks.
// Old prep: every lane-load touched a distinct cache line (stride 11776 B
// across lanes).  New prep: HBM read is perfectly streamed.
// ===========================================================================
__global__ __launch_bounds__(256) void prep_fast(
    const float* __restrict__ coeffs, char* __restrict__ cp2) {
    __shared__ float slab[256 * LC];   // 23552 B
    const size_t base = (size_t)blockIdx.x * 256;   // first (i,j) pair
    // ---- coalesced slab load: 1472 float4 = 256 pairs x 23 f32 ----
    {
        const float4* g4 = reinterpret_cast<const float4*>(coeffs + base * LC);
        float4* s4 = reinterpret_cast<float4*>(slab);
        for (int it = threadIdx.x; it < (256 * LC) / 4; it += 256)
            s4[it] = g4[it];
    }
    __syncthreads();
    // ---- repack one (i,j) per thread ----
    const int t = (int)base + threadIdx.x;   // pair index = i*128 + j
    const int i = t >> 7;
    const int j = t & 127;
    const float* my = slab + threadIdx.x * LC;
    const int g = i >> 4;
    const int col = i & 15;
    char* row = cp2 + (size_t)(j * 16 + g) * BROW + col * 16;
    f16x8 w0, w1, w2;
#pragma unroll
    for (int e = 0; e < 8; ++e) {
        w0[e] = (_Float16)my[e];
        w1[e] = (_Float16)my[8 + e];
        w2[e] = (e < 4) ? (_Float16)my[16 + e] : (_Float16)0.0f;
    }
    *reinterpret_cast<f16x8*>(row) = w0;          // q0: slots 0-7
    *reinterpret_cast<f16x8*>(row + 256) = w1;    // q1: slots 8-15
    *reinterpret_cast<f16x8*>(row + 512) = w2;    // q2: slots 16-19 (+zeros)
}

// ===========================================================================
// kan_mfma8 (R8-verified, UNCHANGED): out = W * C via mfma_f32_16x16x32_f16.
//   Block: 512 thr = 8 INDEPENDENT waves; wave ks owns j in [ks*16,ks*16+16).
//   Block tile 64 x 64 (bn in [0,4)); wave computes the full 64x64 partial
//   (mf=4 x nf=4).  Grid = 128 mb x 4 bn = 512 -> 2 blocks/CU, 16 waves/CU.
// Phase 0: meta (sigmoid/bin/weights) -> 64 KiB LDS.
// K-loop: ping-pong B-frag prefetch (2x unrolled); au rebuilt per mf.
//   q=3 lanes re-read q=2 bytes (A-frag there is structurally zero).
// Epilogue: 8-partial reduce in 2 half-passes, XOR-16 swizzle.
// ===========================================================================
__global__ __launch_bounds__(512, 4) void kan_mfma8(
    const float* __restrict__ x, const char* __restrict__ cp2,
    float* __restrict__ out) {
    __shared__ uint2 mlds[IN_F][64];   // 64 KiB: [j][row] meta

    const int tid = threadIdx.x;
    const int lane = tid & 63;
    const int ks = tid >> 6;           // wave id = K-split id [0,8)
    const int l15 = lane & 15;
    const int q = lane >> 4;
    const int q4 = q * 4;
    const int qc = (q < 3) ? q : 2;    // q=3 reads q=2's bytes (A=0 there)

    // bijective XCD swizzle (512 = 8 * 64)
    int wg = (blockIdx.x & 7) * 64 + (blockIdx.x >> 3);
    const int mb = wg >> 2;   // [0,128)
    const int bn = wg & 3;    // [0,4)
    const int b0 = mb * 64;

    // ---- Phase 0: meta for 64 rows x 128 j into LDS ----
    {
        const int row = lane;              // rows 0..63
        const int jb = ks * 16;            // 8 waves x 16 j
        const float4* xr = reinterpret_cast<const float4*>(
            x + (size_t)(b0 + row) * IN_F + jb);
#pragma unroll
        for (int u = 0; u < 4; ++u) {
            float4 xv = xr[u];
#pragma unroll
            for (int e = 0; e < 4; ++e) {
                float xvv = (e == 0) ? xv.x : (e == 1) ? xv.y
                           : (e == 2) ? xv.z : xv.w;
                float s = 1.0f / (1.0f + __expf(-xvv));
                float idxf = s * 19.0f;
                int k = (int)idxf;            // floor (idxf >= 0)
                k = (k > 18) ? 18 : k;
                float w1 = idxf - (float)k;
                float w0 = 1.0f - w1;
                unsigned u0 = __half_as_ushort(__float2half(w0));
                unsigned u1 = __half_as_ushort(__float2half(w1));
                unsigned lo, hi;
                if (k & 1) { lo = u0 << 16; hi = u1; }
                else       { lo = u0 | (u1 << 16); hi = 0u; }
                unsigned P = (unsigned)(k >> 1);
                mlds[jb + u * 4 + e][row] = uint2{lo, hi | (P << 16)};
            }
        }
    }
    __syncthreads();

    // ---- K-loop ----
    const int j0 = ks * JPW;
    const char* bbase = cp2 + (size_t)(bn * 4) * BROW + qc * 256 + l15 * 16;
    auto bld = [&](int j, int nf) {
        return *reinterpret_cast<const f16x8*>(
            bbase + (size_t)(j * 16 + nf) * BROW);
    };

    f32x4 acc[4][4];
#pragma unroll
    for (int mf = 0; mf < 4; ++mf)
#pragma unroll
        for (int nf = 0; nf < 4; ++nf) acc[mf][nf] = f32x4{0.f, 0.f, 0.f, 0.f};

    f16x8 rc[4], rn[4];
#pragma unroll
    for (int h = 0; h < 4; ++h) rc[h] = bld(j0, h);

    auto step = [&](f16x8 (&cur)[4], f16x8 (&nxt)[4], int j, int jn) {
        // prefetch next j's B-frags (land under A-build + MFMA)
#pragma unroll
        for (int h = 0; h < 4; ++h) nxt[h] = bld(jn, h);
#pragma unroll
        for (int mf = 0; mf < 4; ++mf) {
            uint2 m = mlds[j][mf * 16 + l15];
            unsigned lo = m.x;
            unsigned hi = m.y & 0xFFFFu;
            int d = (int)(m.y >> 16) - q4;
            union { uint32_t u[4]; f16x8 h; } au;
#pragma unroll
            for (int r = 0; r < 4; ++r) {
                uint32_t v = (d == r) ? lo : 0u;
                v = (d == r - 1) ? hi : v;
                au.u[r] = v;
            }
#pragma unroll
            for (int nf = 0; nf < 4; ++nf)
                acc[mf][nf] = __builtin_amdgcn_mfma_f32_16x16x32_f16(
                    au.h, cur[nf], acc[mf][nf], 0, 0, 0);
        }
    };

    for (int jj = 0; jj < JPW; jj += 2) {
        step(rc, rn, j0 + jj, j0 + jj + 1);
        step(rn, rc, j0 + jj + 1, j0 + ((jj + 2) & (JPW - 1)));  // wrap
    }

    // ---- Epilogue: reduce 8 wave-partials in 2 column-half passes ----
    __syncthreads();   // all waves done reading mlds
    float* red = reinterpret_cast<float*>(&mlds[0][0]);   // 16384 f32
#pragma unroll
    for (int p = 0; p < 2; ++p) {
        if (p) __syncthreads();   // previous pass's reads complete
        // wave ks writes its 64x32 half: C/D layout col=l15, row=q4+r
        // XOR-16 swizzle on col by (q&1): write banks 2-way (free)
#pragma unroll
        for (int mf = 0; mf < 4; ++mf)
#pragma unroll
            for (int t = 0; t < 2; ++t)
#pragma unroll
                for (int r = 0; r < 4; ++r) {
                    int colsw = (t * 16 + l15 + (q & 1) * 16) & 31;
                    red[ks * 2048 + (mf * 16 + q4 + r) * 32 + colsw] =
                        acc[mf][p * 2 + t][r];
                }
        __syncthreads();
#pragma unroll
        for (int it = 0; it < 4; ++it) {
            int idx = it * 512 + tid;   // [0,2048) = [64 rows][32 cols]
            int row = idx >> 5;
            int col = idx & 31;
            int colsw = (col + ((row >> 2) & 1) * 16) & 31;
            float s = 0.f;
#pragma unroll
            for (int w = 0; w < 8; ++w) s += red[w * 2048 + row * 32 + colsw];
            out[(size_t)(b0 + row) * OUT_F + bn * 64 + p * 32 + col] = s;
        }
    }
}

// ===========================================================================
// Fallback paths (R2-validated) — used only if d_ws is too small.
// ===========================================================================
__device__ __forceinline__ float dot2_acc(unsigned cbits, unsigned wbits,
                                          float acc) {
#if __has_builtin(__builtin_amdgcn_fdot2)
    union { unsigned u; half2v h; } c, w;
    c.u = cbits; w.u = wbits;
    return __builtin_amdgcn_fdot2(c.h, w.h, acc, false);
#else
    __half2 hc = *reinterpret_cast<const __half2*>(&cbits);
    __half2 hw = *reinterpret_cast<const __half2*>(&wbits);
    float2 fc = __half22float2(hc);
    float2 fw = __half22float2(hw);
    return acc + fc.x * fw.x + fc.y * fw.y;
#endif
}

__global__ __launch_bounds__(256) void build_ctg_kernel(
    const float* __restrict__ coeffs, unsigned short* __restrict__ ctg) {
    int tid = blockIdx.x * 256 + threadIdx.x;
    int qq = tid & 63;
    int k = (tid >> 6) % LC;
    int j = tid / (64 * LC);
    if (j >= IN_F) return;
    int k1 = (k + 1 < LC) ? (k + 1) : (LC - 1);
    union { unsigned short h[8]; uint4 v; } u;
#pragma unroll
    for (int c = 0; c < 4; ++c) {
        int i = qq * 4 + c;
        const float* base = coeffs + ((size_t)i * IN_F + j) * LC;
        u.h[2 * c]     = __half_as_ushort(__float2half(base[k]));
        u.h[2 * c + 1] = __half_as_ushort(__float2half(base[k1]));
    }
    reinterpret_cast<uint4*>(ctg)[tid] = u.v;
}

__global__ __launch_bounds__(256) void kan_main_kernel(
    const float* __restrict__ x, const char* __restrict__ ctg,
    float* __restrict__ out) {
    __shared__ unsigned metas[4][2 * IN_F];
    const int wave = threadIdx.x >> 6;
    const int lane = threadIdx.x & 63;
    const int b = blockIdx.x * 4 + wave;
    float2 xv = reinterpret_cast<const float2*>(x + (size_t)b * IN_F)[lane];
    uint4 m;
#pragma unroll
    for (int t = 0; t < 2; ++t) {
        float xs = t ? xv.y : xv.x;
        float s = 1.0f / (1.0f + __expf(-xs));
        float idxf = s * 19.0f;
        int k = (int)idxf;
        k = (k > 18) ? 18 : k;
        float w1 = idxf - (float)k;
        float w0 = 1.0f - w1;
        int j = 2 * lane + t;
        unsigned off = (unsigned)((j * LC + k) << 10);
        half2v w; w[0] = (_Float16)w0; w[1] = (_Float16)w1;
        unsigned wbits = *reinterpret_cast<unsigned*>(&w);
        if (t == 0) { m.x = off; m.y = wbits; }
        else        { m.z = off; m.w = wbits; }
    }
    reinterpret_cast<uint4*>(&metas[wave][0])[lane] = m;
    __syncthreads();
    const unsigned lanebase = lane * 16;
    const uint4* mrow = reinterpret_cast<const uint4*>(&metas[wave][0]);
    float acc0 = 0.f, acc1 = 0.f, acc2 = 0.f, acc3 = 0.f;
#pragma unroll 8
    for (int j2 = 0; j2 < IN_F / 2; ++j2) {
        uint4 mm = mrow[j2];
        {
            const uint4 e = *reinterpret_cast<const uint4*>(
                ctg + (size_t)(lanebase + mm.x));
            acc0 = dot2_acc(e.x, mm.y, acc0);
            acc1 = dot2_acc(e.y, mm.y, acc1);
            acc2 = dot2_acc(e.z, mm.y, acc2);
            acc3 = dot2_acc(e.w, mm.y, acc3);
        }
        {
            const uint4 e = *reinterpret_cast<const uint4*>(
                ctg + (size_t)(lanebase + mm.z));
            acc0 = dot2_acc(e.x, mm.w, acc0);
            acc1 = dot2_acc(e.y, mm.w, acc1);
            acc2 = dot2_acc(e.z, mm.w, acc2);
            acc3 = dot2_acc(e.w, mm.w, acc3);
        }
    }
    float4 r = make_float4(acc0, acc1, acc2, acc3);
    reinterpret_cast<float4*>(out + (size_t)b * OUT_F)[lane] = r;
}

// ===========================================================================
extern "C" void kernel_launch(void* const* d_in, const int* in_sizes, int n_in,
                              void* d_out, int out_size, void* d_ws,
                              size_t ws_size, hipStream_t stream) {
    const float* x = (const float*)d_in[0];       // [8192, 128] f32
    const float* coeffs = (const float*)d_in[1];  // [256, 128, 23] f32
    float* out = (float*)d_out;                   // [8192, 256] f32

    const size_t cp2_bytes = (size_t)IN_F * 16 * BROW;           // 1.5 MiB
    const size_t ctg_bytes = (size_t)IN_F * LC * 64 * 16;        // ~2.9 MiB

    if (d_ws != nullptr && ws_size >= cp2_bytes) {
        char* cp2 = (char*)d_ws;
        // coalesced prep: 32768 (i,j) pairs, 256/block -> 128 blocks
        prep_fast<<<128, 256, 0, stream>>>(coeffs, cp2);
        kan_mfma8<<<512, 512, 0, stream>>>(x, cp2, out);
    } else if (d_ws != nullptr && ws_size >= ctg_bytes) {
        char* ctg = (char*)d_ws;
        const int totalA = IN_F * LC * 64;
        build_ctg_kernel<<<(totalA + 255) / 256, 256, 0, stream>>>(
            coeffs, (unsigned short*)ctg);
        kan_main_kernel<<<BATCH / 4, 256, 0, stream>>>(x, ctg, out);
    } else {
        kan_main_kernel<<<BATCH / 4, 256, 0, stream>>>(x, (const char*)d_ws,
                                                       out);
    }
}